// Round 2
// baseline (4288.742 us; speedup 1.0000x reference)
//
#include <hip/hip_runtime.h>
#include <math.h>

// Problem constants (fixed by the reference)
#define NN      32768
#define EE_N    262144
#define LL      4
#define HID     512
#define IN_DIM  386
#define OUT_DIM 384
#define EDIM    32
#define MAX_SP  4

// ---------------------------------------------------------------------------
// bf16 helpers (bit-level, RNE)
// ---------------------------------------------------------------------------
__device__ __forceinline__ unsigned short f2bf(float f) {
    unsigned int u = __float_as_uint(f);
    unsigned int r = (u + 0x7FFFu + ((u >> 16) & 1u)) >> 16;
    return (unsigned short)r;
}
__device__ __forceinline__ float bf2f(unsigned short s) {
    return __uint_as_float(((unsigned int)s) << 16);
}
// unpack a uint holding two bf16 (little-endian: low half = element 0)
__device__ __forceinline__ void unpack2(unsigned int w, float& lo, float& hi) {
    lo = __uint_as_float(w << 16);
    hi = __uint_as_float(w & 0xFFFF0000u);
}

// ---------------------------------------------------------------------------
// GEMM: C[M,N] = A[M,K] @ B[K,N] + bias[N]   (f32 math, 128x128 tile, BK=16)
// 256 threads, each computes 8x8 outputs. A staged via float2 (8B-aligned for
// K=386 and K=512). C written as f32 or bf16 per template.
// ---------------------------------------------------------------------------
template <bool BF16_OUT>
__global__ __launch_bounds__(256) void gemm_f32(
    const float* __restrict__ A, const float* __restrict__ B,
    const float* __restrict__ bias, void* __restrict__ Cv,
    int M, int K, int N)
{
    __shared__ float As[16][132];  // [k][row], padded
    __shared__ float Bs[16][132];  // [k][col], padded

    const int t   = threadIdx.x;
    const int tx  = t & 15, ty = t >> 4;
    const int row0 = blockIdx.y * 128;
    const int col0 = blockIdx.x * 128;

    float acc[8][8];
#pragma unroll
    for (int i = 0; i < 8; ++i)
#pragma unroll
        for (int j = 0; j < 8; ++j) acc[i][j] = 0.f;

    const int ar  = t >> 2;         // A row within tile half (0..63)
    const int akq = (t & 3) << 2;   // A k-offset (0,4,8,12)
    const int bk  = t >> 5;         // B k within tile half (0..7)
    const int bc  = (t & 31) << 2;  // B col offset (0..124)

    for (int kt = 0; kt < K; kt += 16) {
        if (kt + 16 <= K) {
#pragma unroll
            for (int half = 0; half < 2; ++half) {
                int r = ar + half * 64;
                const float* ap = &A[(size_t)(row0 + r) * K + kt + akq];
                float2 a0 = *reinterpret_cast<const float2*>(ap);       // 8B aligned
                float2 a1 = *reinterpret_cast<const float2*>(ap + 2);
                As[akq + 0][r] = a0.x;
                As[akq + 1][r] = a0.y;
                As[akq + 2][r] = a1.x;
                As[akq + 3][r] = a1.y;
            }
#pragma unroll
            for (int half = 0; half < 2; ++half) {
                int kk = bk + half * 8;
                float4 bv = *reinterpret_cast<const float4*>(&B[(size_t)(kt + kk) * N + col0 + bc]);
                *reinterpret_cast<float4*>(&Bs[kk][bc]) = bv;
            }
        } else {  // partial K tile (K=386 case): zero-fill
#pragma unroll
            for (int half = 0; half < 2; ++half) {
                int r = ar + half * 64;
#pragma unroll
                for (int c = 0; c < 4; ++c) {
                    int kg = kt + akq + c;
                    As[akq + c][r] = (kg < K) ? A[(size_t)(row0 + r) * K + kg] : 0.f;
                }
            }
#pragma unroll
            for (int half = 0; half < 2; ++half) {
                int kk = bk + half * 8;
                float4 bv = make_float4(0.f, 0.f, 0.f, 0.f);
                if (kt + kk < K)
                    bv = *reinterpret_cast<const float4*>(&B[(size_t)(kt + kk) * N + col0 + bc]);
                *reinterpret_cast<float4*>(&Bs[kk][bc]) = bv;
            }
        }
        __syncthreads();

#pragma unroll
        for (int kk = 0; kk < 16; ++kk) {
            float4 a0 = *reinterpret_cast<const float4*>(&As[kk][ty * 8]);
            float4 a1 = *reinterpret_cast<const float4*>(&As[kk][ty * 8 + 4]);
            float4 b0 = *reinterpret_cast<const float4*>(&Bs[kk][tx * 8]);
            float4 b1 = *reinterpret_cast<const float4*>(&Bs[kk][tx * 8 + 4]);
            float av[8] = {a0.x, a0.y, a0.z, a0.w, a1.x, a1.y, a1.z, a1.w};
            float bv[8] = {b0.x, b0.y, b0.z, b0.w, b1.x, b1.y, b1.z, b1.w};
#pragma unroll
            for (int i = 0; i < 8; ++i)
#pragma unroll
                for (int j = 0; j < 8; ++j) acc[i][j] = fmaf(av[i], bv[j], acc[i][j]);
        }
        __syncthreads();
    }

#pragma unroll
    for (int i = 0; i < 8; ++i) {
        const int row = row0 + ty * 8 + i;
        const int col = col0 + tx * 8;
        float o[8];
#pragma unroll
        for (int j = 0; j < 8; ++j) o[j] = acc[i][j] + bias[col + j];
        if (BF16_OUT) {
            unsigned short* C = (unsigned short*)Cv;
            union { unsigned short us[8]; uint4 v; } pk;
#pragma unroll
            for (int j = 0; j < 8; ++j) pk.us[j] = f2bf(o[j]);
            *reinterpret_cast<uint4*>(&C[(size_t)row * N + col]) = pk.v;  // 16B aligned
        } else {
            float* C = (float*)Cv;
            float4 o0 = {o[0], o[1], o[2], o[3]};
            float4 o1 = {o[4], o[5], o[6], o[7]};
            *reinterpret_cast<float4*>(&C[(size_t)row * N + col])     = o0;
            *reinterpret_cast<float4*>(&C[(size_t)row * N + col + 4]) = o1;
        }
    }
}

// ---------------------------------------------------------------------------
// ee table: ee[a][j] = sum_k Etab[a][k] * We[k][j] + be[j]   (a<4, j<512)
// ---------------------------------------------------------------------------
__global__ void ee_kernel(const float* __restrict__ Etab,
                          const float* __restrict__ We,
                          const float* __restrict__ be,
                          float* __restrict__ ee)
{
    int j = threadIdx.x;
    if (j < HID) {
        for (int a = 0; a < MAX_SP; ++a) {
            float s = be[j];
            for (int kk = 0; kk < EDIM; ++kk)
                s = fmaf(Etab[a * EDIM + kk], We[kk * HID + j], s);
            ee[a * HID + j] = s;
        }
    }
}

// ---------------------------------------------------------------------------
// CSR build: histogram -> scan -> scatter
// ---------------------------------------------------------------------------
__global__ void hist_kernel(const int* __restrict__ dst, int* __restrict__ deg)
{
    int e = blockIdx.x * blockDim.x + threadIdx.x;
    if (e < EE_N) atomicAdd(&deg[dst[e]], 1);
}

__global__ __launch_bounds__(1024) void scan_kernel(
    const int* __restrict__ deg, int* __restrict__ row_ptr, int* __restrict__ cursor)
{
    __shared__ int sdata[1024];
    const int t = threadIdx.x;
    const int base = t * 32;   // 1024 * 32 == 32768
    int s = 0;
    for (int i = 0; i < 32; ++i) s += deg[base + i];
    sdata[t] = s;
    __syncthreads();
    for (int off = 1; off < 1024; off <<= 1) {
        int val = (t >= off) ? sdata[t - off] : 0;
        __syncthreads();
        sdata[t] += val;
        __syncthreads();
    }
    int run = sdata[t] - s;   // exclusive prefix
    for (int i = 0; i < 32; ++i) {
        row_ptr[base + i] = run;
        cursor[base + i]  = run;
        run += deg[base + i];
    }
    if (t == 1023) row_ptr[NN] = run;
}

__global__ void scatter_kernel(const int* __restrict__ src, const int* __restrict__ dst,
                               const int* __restrict__ aid, int* __restrict__ cursor,
                               int* __restrict__ csr_src, int* __restrict__ csr_aid)
{
    int e = blockIdx.x * blockDim.x + threadIdx.x;
    if (e < EE_N) {
        int d = dst[e];
        int pos = atomicAdd(&cursor[d], 1);
        csr_src[pos] = src[e];
        csr_aid[pos] = aid[e];
    }
}

// ---------------------------------------------------------------------------
// Attention: one wave per dst node, single-pass online softmax over incoming
// edges. q/k/v are bf16; math f32; lane = h*8+dg owns dims [lane*8, +8).
// out (bf16) may alias q (each wave reads only its own q row before writing).
// ---------------------------------------------------------------------------
__global__ __launch_bounds__(256) void attn_kernel(
    const unsigned short* __restrict__ q, const unsigned short* __restrict__ k,
    const unsigned short* __restrict__ v, const float* __restrict__ ee,
    const int* __restrict__ row_ptr, const int* __restrict__ csr_src,
    const int* __restrict__ csr_aid, unsigned short* __restrict__ out)
{
    __shared__ float ees[MAX_SP * HID];
    const int t = threadIdx.x;
    for (int i = t; i < MAX_SP * HID; i += 256) ees[i] = ee[i];
    __syncthreads();

    const int wave = t >> 6, lane = t & 63;
    const int node = blockIdx.x * 4 + wave;
    const int off  = lane << 3;               // == h*64 + dg*8

    float qa[8];
    {
        uint4 qv = *reinterpret_cast<const uint4*>(&q[(size_t)node * HID + off]);
        unpack2(qv.x, qa[0], qa[1]); unpack2(qv.y, qa[2], qa[3]);
        unpack2(qv.z, qa[4], qa[5]); unpack2(qv.w, qa[6], qa[7]);
    }

    float m = -INFINITY, denom = 0.f;
    float acc[8] = {0.f, 0.f, 0.f, 0.f, 0.f, 0.f, 0.f, 0.f};

    const int beg = row_ptr[node], end = row_ptr[node + 1];
    for (int i = beg; i < end; ++i) {
        const int s   = csr_src[i];
        const int aid = csr_aid[i];
        const float* ep = &ees[aid * HID + off];

        float kj[8];
        {
            uint4 kv = *reinterpret_cast<const uint4*>(&k[(size_t)s * HID + off]);
            unpack2(kv.x, kj[0], kj[1]); unpack2(kv.y, kj[2], kj[3]);
            unpack2(kv.z, kj[4], kj[5]); unpack2(kv.w, kj[6], kj[7]);
        }
        float partial = 0.f;
#pragma unroll
        for (int j = 0; j < 8; ++j) partial = fmaf(qa[j], kj[j] + ep[j], partial);
        partial += __shfl_xor(partial, 1);
        partial += __shfl_xor(partial, 2);
        partial += __shfl_xor(partial, 4);   // full per-head dot (8 lanes/head)
        const float alpha = partial * 0.125f;  // 1/sqrt(64)

        const float mnew = fmaxf(m, alpha);
        const float corr = expf(m - mnew);     // 0 on first edge (m=-inf)
        const float w    = expf(alpha - mnew);
        denom = denom * corr + w;

        float vj[8];
        {
            uint4 vv = *reinterpret_cast<const uint4*>(&v[(size_t)s * HID + off]);
            unpack2(vv.x, vj[0], vj[1]); unpack2(vv.y, vj[2], vj[3]);
            unpack2(vv.z, vj[4], vj[5]); unpack2(vv.w, vj[6], vj[7]);
        }
#pragma unroll
        for (int j = 0; j < 8; ++j) acc[j] = acc[j] * corr + w * (vj[j] + ep[j]);
        m = mnew;
    }

    const float inv = (denom > 0.f) ? (1.f / denom) : 0.f;  // deg-0 node -> 0
    union { unsigned short us[8]; uint4 v4; } pk;
#pragma unroll
    for (int j = 0; j < 8; ++j) pk.us[j] = f2bf(acc[j] * inv);
    *reinterpret_cast<uint4*>(&out[(size_t)node * HID + off]) = pk.v4;
}

// ---------------------------------------------------------------------------
// beta-gate + residual + LayerNorm, one wave per node (lane owns 8 dims).
// beta = sigmoid(out.(w1+w3) + xr.(w2-w3) + b);  h = LN(h + beta*xr+(1-b)*out)
// attn/xr are bf16; h is f32 (read+write).
// ---------------------------------------------------------------------------
__global__ __launch_bounds__(256) void blend_ln_kernel(
    float* __restrict__ h, const unsigned short* __restrict__ attn,
    const unsigned short* __restrict__ xr, const float* __restrict__ wbeta,
    const float* __restrict__ bbeta, const float* __restrict__ ln_g,
    const float* __restrict__ ln_b)
{
    const int t = threadIdx.x;
    const int wave = t >> 6, lane = t & 63;
    const int node = blockIdx.x * 4 + wave;
    const int off  = lane << 3;

    float o8[8], x8[8], h8[8];
    {
        uint4 a = *reinterpret_cast<const uint4*>(&attn[(size_t)node * HID + off]);
        unpack2(a.x, o8[0], o8[1]); unpack2(a.y, o8[2], o8[3]);
        unpack2(a.z, o8[4], o8[5]); unpack2(a.w, o8[6], o8[7]);
        uint4 b = *reinterpret_cast<const uint4*>(&xr[(size_t)node * HID + off]);
        unpack2(b.x, x8[0], x8[1]); unpack2(b.y, x8[2], x8[3]);
        unpack2(b.z, x8[4], x8[5]); unpack2(b.w, x8[6], x8[7]);
        float4 c0 = *reinterpret_cast<const float4*>(&h[(size_t)node * HID + off]);
        float4 c1 = *reinterpret_cast<const float4*>(&h[(size_t)node * HID + off + 4]);
        h8[0]=c0.x; h8[1]=c0.y; h8[2]=c0.z; h8[3]=c0.w; h8[4]=c1.x; h8[5]=c1.y; h8[6]=c1.z; h8[7]=c1.w;
    }

    float p = 0.f;
#pragma unroll
    for (int j = 0; j < 8; ++j) {
        float w1 = wbeta[off + j];
        float w2 = wbeta[HID + off + j];
        float w3 = wbeta[2 * HID + off + j];
        p = fmaf(o8[j], w1 + w3, p);
        p = fmaf(x8[j], w2 - w3, p);
    }
#pragma unroll
    for (int m = 1; m <= 32; m <<= 1) p += __shfl_xor(p, m);
    const float beta = 1.f / (1.f + expf(-(p + bbeta[0])));

    float y[8];
    float s = 0.f;
#pragma unroll
    for (int j = 0; j < 8; ++j) {
        y[j] = h8[j] + beta * x8[j] + (1.f - beta) * o8[j];
        s += y[j];
    }
#pragma unroll
    for (int m = 1; m <= 32; m <<= 1) s += __shfl_xor(s, m);
    const float mean = s * (1.f / HID);

    float vs = 0.f;
#pragma unroll
    for (int j = 0; j < 8; ++j) {
        float d = y[j] - mean;
        vs = fmaf(d, d, vs);
    }
#pragma unroll
    for (int m = 1; m <= 32; m <<= 1) vs += __shfl_xor(vs, m);
    const float rstd = rsqrtf(vs * (1.f / HID) + 1e-5f);

    float rr[8];
#pragma unroll
    for (int j = 0; j < 8; ++j)
        rr[j] = (y[j] - mean) * rstd * ln_g[off + j] + ln_b[off + j];
    float4 r0 = {rr[0], rr[1], rr[2], rr[3]};
    float4 r1 = {rr[4], rr[5], rr[6], rr[7]};
    *reinterpret_cast<float4*>(&h[(size_t)node * HID + off])     = r0;
    *reinterpret_cast<float4*>(&h[(size_t)node * HID + off + 4]) = r1;
}

// ---------------------------------------------------------------------------
extern "C" void kernel_launch(void* const* d_in, const int* in_sizes, int n_in,
                              void* d_out, int out_size, void* d_ws, size_t ws_size,
                              hipStream_t stream)
{
    const float* emb   = (const float*)d_in[0];
    const int*   eidx  = (const int*)d_in[1];
    const int*   aid   = (const int*)d_in[2];
    const float* Win   = (const float*)d_in[3];
    const float* bin_  = (const float*)d_in[4];
    const float* Etab  = (const float*)d_in[5];
    const float* Wq    = (const float*)d_in[6];
    const float* bq    = (const float*)d_in[7];
    const float* Wk    = (const float*)d_in[8];
    const float* bk    = (const float*)d_in[9];
    const float* Wv    = (const float*)d_in[10];
    const float* bv    = (const float*)d_in[11];
    const float* We    = (const float*)d_in[12];
    const float* be    = (const float*)d_in[13];
    const float* Ws    = (const float*)d_in[14];
    const float* bs    = (const float*)d_in[15];
    const float* Wbeta = (const float*)d_in[16];
    const float* bbeta = (const float*)d_in[17];
    const float* ln_g  = (const float*)d_in[18];
    const float* ln_b  = (const float*)d_in[19];
    const float* Wout  = (const float*)d_in[20];
    const float* bout  = (const float*)d_in[21];
    float* out = (float*)d_out;

    // workspace layout — total ~162.4 MiB (h f32; q/k/v bf16; CSR)
    char* w = (char*)d_ws;
    float* h = (float*)w;            w += (size_t)NN * HID * 4;   // 64 MB
    unsigned short* q = (unsigned short*)w; w += (size_t)NN * HID * 2;  // 32 MB
    unsigned short* k = (unsigned short*)w; w += (size_t)NN * HID * 2;  // 32 MB
    unsigned short* v = (unsigned short*)w; w += (size_t)NN * HID * 2;  // 32 MB
    float* ee = (float*)w;           w += MAX_SP * HID * 4;
    int* row_ptr = (int*)w;          w += (NN + 4) * 4;
    int* cursor  = (int*)w;          w += NN * 4;
    int* deg     = (int*)w;          w += NN * 4;
    int* csr_src = (int*)w;          w += EE_N * 4;
    int* csr_aid = (int*)w;          w += EE_N * 4;

    const int* src = eidx;            // edge_index[0]
    const int* dst = eidx + EE_N;     // edge_index[1]

    // CSR build (inputs are restored每 call, so rebuild every launch)
    hipMemsetAsync(deg, 0, NN * sizeof(int), stream);
    hist_kernel<<<EE_N / 256, 256, 0, stream>>>(dst, deg);
    scan_kernel<<<1, 1024, 0, stream>>>(deg, row_ptr, cursor);
    scatter_kernel<<<EE_N / 256, 256, 0, stream>>>(src, dst, aid, cursor, csr_src, csr_aid);

    // h = emb @ Win + bin   (f32 out)
    gemm_f32<false><<<dim3(HID / 128, NN / 128), 256, 0, stream>>>(emb, Win, bin_, h, NN, IN_DIM, HID);

    for (int l = 0; l < LL; ++l) {
        ee_kernel<<<1, HID, 0, stream>>>(Etab, We + (size_t)l * EDIM * HID, be + l * HID, ee);
        gemm_f32<true><<<dim3(HID / 128, NN / 128), 256, 0, stream>>>(h, Wq + (size_t)l * HID * HID, bq + l * HID, q, NN, HID, HID);
        gemm_f32<true><<<dim3(HID / 128, NN / 128), 256, 0, stream>>>(h, Wk + (size_t)l * HID * HID, bk + l * HID, k, NN, HID, HID);
        gemm_f32<true><<<dim3(HID / 128, NN / 128), 256, 0, stream>>>(h, Wv + (size_t)l * HID * HID, bv + l * HID, v, NN, HID, HID);
        // attention writes its result over q (safe: each wave reads only its own q row first)
        attn_kernel<<<NN / 4, 256, 0, stream>>>(q, k, v, ee, row_ptr, csr_src, csr_aid, q);
        // xr = h @ Ws + bs, into k (k is dead after attn)
        gemm_f32<true><<<dim3(HID / 128, NN / 128), 256, 0, stream>>>(h, Ws + (size_t)l * HID * HID, bs + l * HID, k, NN, HID, HID);
        blend_ln_kernel<<<NN / 4, 256, 0, stream>>>(h, q, k, Wbeta + (size_t)l * 3 * HID, bbeta + l,
                                                    ln_g + l * HID, ln_b + l * HID);
    }

    // out = h @ Wout + bout  (f32 out)
    gemm_f32<false><<<dim3(OUT_DIM / 128, NN / 128), 256, 0, stream>>>(h, Wout, bout, out, NN, HID, OUT_DIM);
}

// Round 3
// 1392.245 us; speedup vs baseline: 3.0805x; 3.0805x over previous
//
#include <hip/hip_runtime.h>
#include <math.h>

// Problem constants (fixed by the reference)
#define NN      32768
#define EE_N    262144
#define LL      4
#define HID     512
#define IN_DIM  386
#define KP_IN   416      // IN_DIM padded to multiple of 32
#define OUT_DIM 384
#define EDIM    32
#define MAX_SP  4

typedef __attribute__((ext_vector_type(8))) __bf16 bf16x8;
typedef __attribute__((ext_vector_type(4))) float  f32x4;

// ---------------------------------------------------------------------------
// bf16 helpers (bit-level, RNE)
// ---------------------------------------------------------------------------
__device__ __forceinline__ unsigned short f2bf(float f) {
    unsigned int u = __float_as_uint(f);
    unsigned int r = (u + 0x7FFFu + ((u >> 16) & 1u)) >> 16;
    return (unsigned short)r;
}
__device__ __forceinline__ void unpack2(unsigned int w, float& lo, float& hi) {
    lo = __uint_as_float(w << 16);
    hi = __uint_as_float(w & 0xFFFF0000u);
}

// ---------------------------------------------------------------------------
// MFMA GEMM: C[M,N] = A[M,Kp](bf16) @ Bt[N,Kp](bf16)^T + bias[N](f32)
// 128x128 tile, BK=32, 4 waves, each wave 64x64 via 4x4 frags of 16x16x32.
// Staging via global_load_lds width=16; LDS slot-swizzle (slot = koff ^
// ((row>>1)&3)) applied on the GLOBAL source address (LDS dest stays linear,
// G21), matched on the ds_read side -> 2-way banking (free).
// OUT_MODE: 0 = f32 C0;  1 = bf16 C0;  2 = f32 C0 + bf16 C1.
// ---------------------------------------------------------------------------
template <int OUT_MODE>
__global__ __launch_bounds__(256) void gemm_mfma(
    const unsigned short* __restrict__ A,   // [M][Kp] bf16 row-major
    const unsigned short* __restrict__ Bt,  // [N][Kp] bf16 (W transposed)
    const float* __restrict__ bias,
    void* __restrict__ C0, void* __restrict__ C1,
    int M, int Kp, int N)
{
    __shared__ unsigned short As[128 * 32];  // row r at byte r*64, 4 slots of 16B
    __shared__ unsigned short Bs[128 * 32];  // col c at byte c*64

    const int t    = threadIdx.x;
    const int lane = t & 63, wid = t >> 6;
    const int wr   = wid >> 1, wc = wid & 1;        // 2x2 wave grid
    const int row0 = blockIdx.y * 128;
    const int col0 = blockIdx.x * 128;

    f32x4 acc[4][4] = {};

    const int srow  = lane >> 2;   // staging: 4 lanes per row (4x16B = 64B row)
    const int sslot = lane & 3;
    const int kq    = lane >> 4;   // ds_read k-quarter (0..3)
    const int l15   = lane & 15;

    for (int kt = 0; kt < Kp; kt += 32) {
#pragma unroll
        for (int i = 0; i < 2; ++i) {
            const int rbase = wid * 32 + i * 16;
            {   // A tile rows [rbase, rbase+16)
                const int r    = rbase + srow;
                const int koff = sslot ^ ((r >> 1) & 3);
                const unsigned short* ga = &A[(size_t)(row0 + r) * Kp + kt + koff * 8];
                __builtin_amdgcn_global_load_lds(
                    (const __attribute__((address_space(1))) unsigned int*)ga,
                    (__attribute__((address_space(3))) unsigned int*)&As[rbase * 32],
                    16, 0, 0);
            }
            {   // B tile cols [rbase, rbase+16)
                const int c    = rbase + srow;
                const int koff = sslot ^ ((c >> 1) & 3);
                const unsigned short* gb = &Bt[(size_t)(col0 + c) * Kp + kt + koff * 8];
                __builtin_amdgcn_global_load_lds(
                    (const __attribute__((address_space(1))) unsigned int*)gb,
                    (__attribute__((address_space(3))) unsigned int*)&Bs[rbase * 32],
                    16, 0, 0);
            }
        }
        __syncthreads();   // compiler drains vmcnt+lgkmcnt before s_barrier

        bf16x8 af[4], bf[4];
#pragma unroll
        for (int mi = 0; mi < 4; ++mi) {
            const int r    = wr * 64 + mi * 16 + l15;
            const int slot = kq ^ ((r >> 1) & 3);
            af[mi] = *reinterpret_cast<const bf16x8*>(&As[r * 32 + slot * 8]);
        }
#pragma unroll
        for (int ni = 0; ni < 4; ++ni) {
            const int c    = wc * 64 + ni * 16 + l15;
            const int slot = kq ^ ((c >> 1) & 3);
            bf[ni] = *reinterpret_cast<const bf16x8*>(&Bs[c * 32 + slot * 8]);
        }
#pragma unroll
        for (int mi = 0; mi < 4; ++mi)
#pragma unroll
            for (int ni = 0; ni < 4; ++ni)
                acc[mi][ni] = __builtin_amdgcn_mfma_f32_16x16x32_bf16(
                    af[mi], bf[ni], acc[mi][ni], 0, 0, 0);
        __syncthreads();
    }

    // epilogue: D frag layout col=lane&15, row=(lane>>4)*4+r  [m89-verified]
    const int cb = col0 + wc * 64;
    const int rb = row0 + wr * 64;
    float bv[4];
#pragma unroll
    for (int ni = 0; ni < 4; ++ni) bv[ni] = bias[cb + ni * 16 + l15];

#pragma unroll
    for (int mi = 0; mi < 4; ++mi) {
#pragma unroll
        for (int ni = 0; ni < 4; ++ni) {
            const int col = cb + ni * 16 + l15;
#pragma unroll
            for (int r = 0; r < 4; ++r) {
                const int row = rb + mi * 16 + kq * 4 + r;
                const float oval = acc[mi][ni][r] + bv[ni];
                if (OUT_MODE == 0) {
                    ((float*)C0)[(size_t)row * N + col] = oval;
                } else if (OUT_MODE == 1) {
                    ((unsigned short*)C0)[(size_t)row * N + col] = f2bf(oval);
                } else {
                    ((float*)C0)[(size_t)row * N + col] = oval;
                    ((unsigned short*)C1)[(size_t)row * N + col] = f2bf(oval);
                }
            }
        }
    }
}

// ---------------------------------------------------------------------------
// Weight convert+transpose: Wt[n][k] = bf16(W[k][n]), zero-pad k in [K, Kp)
// ---------------------------------------------------------------------------
__global__ __launch_bounds__(256) void convert_wt(
    const float* __restrict__ W, unsigned short* __restrict__ Wt,
    int K, int N, int Kp)
{
    __shared__ float tile[32][33];
    const int tx = threadIdx.x, ty = threadIdx.y;
    const int kb = blockIdx.y * 32, nb = blockIdx.x * 32;
#pragma unroll
    for (int i = 0; i < 32; i += 8) {
        const int k = kb + ty + i, n = nb + tx;
        tile[ty + i][tx] = (k < K && n < N) ? W[(size_t)k * N + n] : 0.f;
    }
    __syncthreads();
#pragma unroll
    for (int i = 0; i < 32; i += 8) {
        const int n = nb + ty + i, k = kb + tx;
        if (n < N && k < Kp)
            Wt[(size_t)n * Kp + k] = f2bf(tile[tx][ty + i]);
    }
}

// emb [NN][386] f32 -> ebf [NN][416] bf16 zero-padded
__global__ __launch_bounds__(256) void convert_emb(
    const float* __restrict__ emb, unsigned short* __restrict__ ebf)
{
    const int n = blockIdx.x;
    for (int k = threadIdx.x; k < KP_IN; k += 256)
        ebf[(size_t)n * KP_IN + k] =
            (k < IN_DIM) ? f2bf(emb[(size_t)n * IN_DIM + k]) : (unsigned short)0;
}

// ---------------------------------------------------------------------------
// ee table: ee[a][j] = sum_k Etab[a][k] * We[k][j] + be[j]   (a<4, j<512)
// ---------------------------------------------------------------------------
__global__ void ee_kernel(const float* __restrict__ Etab,
                          const float* __restrict__ We,
                          const float* __restrict__ be,
                          float* __restrict__ ee)
{
    int j = threadIdx.x;
    if (j < HID) {
        for (int a = 0; a < MAX_SP; ++a) {
            float s = be[j];
            for (int kk = 0; kk < EDIM; ++kk)
                s = fmaf(Etab[a * EDIM + kk], We[kk * HID + j], s);
            ee[a * HID + j] = s;
        }
    }
}

// ---------------------------------------------------------------------------
// CSR build: histogram -> scan -> scatter
// ---------------------------------------------------------------------------
__global__ void hist_kernel(const int* __restrict__ dst, int* __restrict__ deg)
{
    int e = blockIdx.x * blockDim.x + threadIdx.x;
    if (e < EE_N) atomicAdd(&deg[dst[e]], 1);
}

__global__ __launch_bounds__(1024) void scan_kernel(
    const int* __restrict__ deg, int* __restrict__ row_ptr, int* __restrict__ cursor)
{
    __shared__ int sdata[1024];
    const int t = threadIdx.x;
    const int base = t * 32;   // 1024 * 32 == 32768
    int s = 0;
    for (int i = 0; i < 32; ++i) s += deg[base + i];
    sdata[t] = s;
    __syncthreads();
    for (int off = 1; off < 1024; off <<= 1) {
        int val = (t >= off) ? sdata[t - off] : 0;
        __syncthreads();
        sdata[t] += val;
        __syncthreads();
    }
    int run = sdata[t] - s;   // exclusive prefix
    for (int i = 0; i < 32; ++i) {
        row_ptr[base + i] = run;
        cursor[base + i]  = run;
        run += deg[base + i];
    }
    if (t == 1023) row_ptr[NN] = run;
}

__global__ void scatter_kernel(const int* __restrict__ src, const int* __restrict__ dst,
                               const int* __restrict__ aid, int* __restrict__ cursor,
                               int* __restrict__ csr_src, int* __restrict__ csr_aid)
{
    int e = blockIdx.x * blockDim.x + threadIdx.x;
    if (e < EE_N) {
        int d = dst[e];
        int pos = atomicAdd(&cursor[d], 1);
        csr_src[pos] = src[e];
        csr_aid[pos] = aid[e];
    }
}

// ---------------------------------------------------------------------------
// Attention: one wave per dst node, single-pass online softmax over incoming
// edges. q/k/v bf16; math f32; lane = h*8+dg owns dims [lane*8, +8).
// out (bf16) may alias q (each wave reads only its own q row before writing).
// ---------------------------------------------------------------------------
__global__ __launch_bounds__(256) void attn_kernel(
    const unsigned short* __restrict__ q, const unsigned short* __restrict__ k,
    const unsigned short* __restrict__ v, const float* __restrict__ ee,
    const int* __restrict__ row_ptr, const int* __restrict__ csr_src,
    const int* __restrict__ csr_aid, unsigned short* __restrict__ out)
{
    __shared__ float ees[MAX_SP * HID];
    const int t = threadIdx.x;
    for (int i = t; i < MAX_SP * HID; i += 256) ees[i] = ee[i];
    __syncthreads();

    const int wave = t >> 6, lane = t & 63;
    const int node = blockIdx.x * 4 + wave;
    const int off  = lane << 3;               // == h*64 + dg*8

    float qa[8];
    {
        uint4 qv = *reinterpret_cast<const uint4*>(&q[(size_t)node * HID + off]);
        unpack2(qv.x, qa[0], qa[1]); unpack2(qv.y, qa[2], qa[3]);
        unpack2(qv.z, qa[4], qa[5]); unpack2(qv.w, qa[6], qa[7]);
    }

    float m = -INFINITY, denom = 0.f;
    float acc[8] = {0.f, 0.f, 0.f, 0.f, 0.f, 0.f, 0.f, 0.f};

    const int beg = row_ptr[node], end = row_ptr[node + 1];
    for (int i = beg; i < end; ++i) {
        const int s   = csr_src[i];
        const int aid = csr_aid[i];
        const float* ep = &ees[aid * HID + off];

        float kj[8];
        {
            uint4 kv = *reinterpret_cast<const uint4*>(&k[(size_t)s * HID + off]);
            unpack2(kv.x, kj[0], kj[1]); unpack2(kv.y, kj[2], kj[3]);
            unpack2(kv.z, kj[4], kj[5]); unpack2(kv.w, kj[6], kj[7]);
        }
        float partial = 0.f;
#pragma unroll
        for (int j = 0; j < 8; ++j) partial = fmaf(qa[j], kj[j] + ep[j], partial);
        partial += __shfl_xor(partial, 1);
        partial += __shfl_xor(partial, 2);
        partial += __shfl_xor(partial, 4);   // full per-head dot (8 lanes/head)
        const float alpha = partial * 0.125f;  // 1/sqrt(64)

        const float mnew = fmaxf(m, alpha);
        const float corr = expf(m - mnew);     // 0 on first edge (m=-inf)
        const float w    = expf(alpha - mnew);
        denom = denom * corr + w;

        float vj[8];
        {
            uint4 vv = *reinterpret_cast<const uint4*>(&v[(size_t)s * HID + off]);
            unpack2(vv.x, vj[0], vj[1]); unpack2(vv.y, vj[2], vj[3]);
            unpack2(vv.z, vj[4], vj[5]); unpack2(vv.w, vj[6], vj[7]);
        }
#pragma unroll
        for (int j = 0; j < 8; ++j) acc[j] = acc[j] * corr + w * (vj[j] + ep[j]);
        m = mnew;
    }

    const float inv = (denom > 0.f) ? (1.f / denom) : 0.f;  // deg-0 node -> 0
    union { unsigned short us[8]; uint4 v4; } pk;
#pragma unroll
    for (int j = 0; j < 8; ++j) pk.us[j] = f2bf(acc[j] * inv);
    *reinterpret_cast<uint4*>(&out[(size_t)node * HID + off]) = pk.v4;
}

// ---------------------------------------------------------------------------
// beta-gate + residual + LayerNorm; writes h (f32) AND hbf (bf16 shadow).
// ---------------------------------------------------------------------------
__global__ __launch_bounds__(256) void blend_ln_kernel(
    float* __restrict__ h, unsigned short* __restrict__ hbf,
    const unsigned short* __restrict__ attn,
    const unsigned short* __restrict__ xr, const float* __restrict__ wbeta,
    const float* __restrict__ bbeta, const float* __restrict__ ln_g,
    const float* __restrict__ ln_b)
{
    const int t = threadIdx.x;
    const int wave = t >> 6, lane = t & 63;
    const int node = blockIdx.x * 4 + wave;
    const int off  = lane << 3;

    float o8[8], x8[8], h8[8];
    {
        uint4 a = *reinterpret_cast<const uint4*>(&attn[(size_t)node * HID + off]);
        unpack2(a.x, o8[0], o8[1]); unpack2(a.y, o8[2], o8[3]);
        unpack2(a.z, o8[4], o8[5]); unpack2(a.w, o8[6], o8[7]);
        uint4 b = *reinterpret_cast<const uint4*>(&xr[(size_t)node * HID + off]);
        unpack2(b.x, x8[0], x8[1]); unpack2(b.y, x8[2], x8[3]);
        unpack2(b.z, x8[4], x8[5]); unpack2(b.w, x8[6], x8[7]);
        float4 c0 = *reinterpret_cast<const float4*>(&h[(size_t)node * HID + off]);
        float4 c1 = *reinterpret_cast<const float4*>(&h[(size_t)node * HID + off + 4]);
        h8[0]=c0.x; h8[1]=c0.y; h8[2]=c0.z; h8[3]=c0.w; h8[4]=c1.x; h8[5]=c1.y; h8[6]=c1.z; h8[7]=c1.w;
    }

    float p = 0.f;
#pragma unroll
    for (int j = 0; j < 8; ++j) {
        float w1 = wbeta[off + j];
        float w2 = wbeta[HID + off + j];
        float w3 = wbeta[2 * HID + off + j];
        p = fmaf(o8[j], w1 + w3, p);
        p = fmaf(x8[j], w2 - w3, p);
    }
#pragma unroll
    for (int m = 1; m <= 32; m <<= 1) p += __shfl_xor(p, m);
    const float beta = 1.f / (1.f + expf(-(p + bbeta[0])));

    float y[8];
    float s = 0.f;
#pragma unroll
    for (int j = 0; j < 8; ++j) {
        y[j] = h8[j] + beta * x8[j] + (1.f - beta) * o8[j];
        s += y[j];
    }
#pragma unroll
    for (int m = 1; m <= 32; m <<= 1) s += __shfl_xor(s, m);
    const float mean = s * (1.f / HID);

    float vs = 0.f;
#pragma unroll
    for (int j = 0; j < 8; ++j) {
        float d = y[j] - mean;
        vs = fmaf(d, d, vs);
    }
#pragma unroll
    for (int m = 1; m <= 32; m <<= 1) vs += __shfl_xor(vs, m);
    const float rstd = rsqrtf(vs * (1.f / HID) + 1e-5f);

    float rr[8];
    union { unsigned short us[8]; uint4 v4; } pk;
#pragma unroll
    for (int j = 0; j < 8; ++j) {
        rr[j] = (y[j] - mean) * rstd * ln_g[off + j] + ln_b[off + j];
        pk.us[j] = f2bf(rr[j]);
    }
    float4 r0 = {rr[0], rr[1], rr[2], rr[3]};
    float4 r1 = {rr[4], rr[5], rr[6], rr[7]};
    *reinterpret_cast<float4*>(&h[(size_t)node * HID + off])     = r0;
    *reinterpret_cast<float4*>(&h[(size_t)node * HID + off + 4]) = r1;
    *reinterpret_cast<uint4*>(&hbf[(size_t)node * HID + off])    = pk.v4;
}

// ---------------------------------------------------------------------------
extern "C" void kernel_launch(void* const* d_in, const int* in_sizes, int n_in,
                              void* d_out, int out_size, void* d_ws, size_t ws_size,
                              hipStream_t stream)
{
    (void)in_sizes; (void)n_in; (void)out_size; (void)ws_size;
    const float* emb   = (const float*)d_in[0];
    const int*   eidx  = (const int*)d_in[1];
    const int*   aid   = (const int*)d_in[2];
    const float* Win   = (const float*)d_in[3];
    const float* bin_  = (const float*)d_in[4];
    const float* Etab  = (const float*)d_in[5];
    const float* Wq    = (const float*)d_in[6];
    const float* bq    = (const float*)d_in[7];
    const float* Wk    = (const float*)d_in[8];
    const float* bk    = (const float*)d_in[9];
    const float* Wv    = (const float*)d_in[10];
    const float* bv    = (const float*)d_in[11];
    const float* We    = (const float*)d_in[12];
    const float* be    = (const float*)d_in[13];
    const float* Ws    = (const float*)d_in[14];
    const float* bs    = (const float*)d_in[15];
    const float* Wbeta = (const float*)d_in[16];
    const float* bbeta = (const float*)d_in[17];
    const float* ln_g  = (const float*)d_in[18];
    const float* ln_b  = (const float*)d_in[19];
    const float* Wout  = (const float*)d_in[20];
    const float* bout  = (const float*)d_in[21];
    float* out = (float*)d_out;

    // workspace layout (~203 MiB).  q overlays the emb-bf16 staging buffer
    // (embbf dead after the input GEMM, which runs before the first q GEMM).
    char* w = (char*)d_ws;
    float* h            = (float*)w;           w += (size_t)NN * HID * 4;   // 64 MB
    unsigned short* q   = (unsigned short*)w;  w += (size_t)NN * HID * 2;   // 32 MB (embbf: NN*416*2 = 27.3 MB fits)
    unsigned short* k   = (unsigned short*)w;  w += (size_t)NN * HID * 2;
    unsigned short* v   = (unsigned short*)w;  w += (size_t)NN * HID * 2;
    unsigned short* hbf = (unsigned short*)w;  w += (size_t)NN * HID * 2;
    unsigned short* embbf = q;                 // overlay
    unsigned short* Winbf  = (unsigned short*)w; w += (size_t)HID * KP_IN * 2;   // [512][416]
    unsigned short* Wlt    = (unsigned short*)w; w += (size_t)16 * HID * HID * 2; // 16 x [512][512]
    unsigned short* Woutbf = (unsigned short*)w; w += (size_t)OUT_DIM * HID * 2;  // [384][512]
    float* ee    = (float*)w;  w += MAX_SP * HID * 4;
    int* row_ptr = (int*)w;    w += (NN + 4) * 4;
    int* cursor  = (int*)w;    w += NN * 4;
    int* deg     = (int*)w;    w += NN * 4;
    int* csr_src = (int*)w;    w += EE_N * 4;
    int* csr_aid = (int*)w;    w += EE_N * 4;

    const int* src = eidx;            // edge_index[0]
    const int* dst = eidx + EE_N;     // edge_index[1]

    // CSR build (inputs restored every call -> rebuild every launch)
    hipMemsetAsync(deg, 0, NN * sizeof(int), stream);
    hist_kernel<<<EE_N / 256, 256, 0, stream>>>(dst, deg);
    scan_kernel<<<1, 1024, 0, stream>>>(deg, row_ptr, cursor);
    scatter_kernel<<<EE_N / 256, 256, 0, stream>>>(src, dst, aid, cursor, csr_src, csr_aid);

    // Weight conversion to bf16 transposed [N][Kp]
    dim3 tb(32, 8);
    convert_wt<<<dim3(HID / 32, KP_IN / 32), tb, 0, stream>>>(Win, Winbf, IN_DIM, HID, KP_IN);
    for (int l = 0; l < LL; ++l) {
        convert_wt<<<dim3(16, 16), tb, 0, stream>>>(Wq + (size_t)l * HID * HID, Wlt + (size_t)(l * 4 + 0) * HID * HID, HID, HID, HID);
        convert_wt<<<dim3(16, 16), tb, 0, stream>>>(Wk + (size_t)l * HID * HID, Wlt + (size_t)(l * 4 + 1) * HID * HID, HID, HID, HID);
        convert_wt<<<dim3(16, 16), tb, 0, stream>>>(Wv + (size_t)l * HID * HID, Wlt + (size_t)(l * 4 + 2) * HID * HID, HID, HID, HID);
        convert_wt<<<dim3(16, 16), tb, 0, stream>>>(Ws + (size_t)l * HID * HID, Wlt + (size_t)(l * 4 + 3) * HID * HID, HID, HID, HID);
    }
    convert_wt<<<dim3(OUT_DIM / 32, HID / 32), tb, 0, stream>>>(Wout, Woutbf, HID, OUT_DIM, HID);
    convert_emb<<<NN, 256, 0, stream>>>(emb, embbf);

    // h = emb @ Win + bin   (f32 h + bf16 hbf)
    gemm_mfma<2><<<dim3(HID / 128, NN / 128), 256, 0, stream>>>(
        embbf, Winbf, bin_, h, hbf, NN, KP_IN, HID);

    for (int l = 0; l < LL; ++l) {
        ee_kernel<<<1, HID, 0, stream>>>(Etab, We + (size_t)l * EDIM * HID, be + l * HID, ee);
        gemm_mfma<1><<<dim3(4, 256), 256, 0, stream>>>(
            hbf, Wlt + (size_t)(l * 4 + 0) * HID * HID, bq + l * HID, q, nullptr, NN, HID, HID);
        gemm_mfma<1><<<dim3(4, 256), 256, 0, stream>>>(
            hbf, Wlt + (size_t)(l * 4 + 1) * HID * HID, bk + l * HID, k, nullptr, NN, HID, HID);
        gemm_mfma<1><<<dim3(4, 256), 256, 0, stream>>>(
            hbf, Wlt + (size_t)(l * 4 + 2) * HID * HID, bv + l * HID, v, nullptr, NN, HID, HID);
        // attention writes over q (each wave reads only its own q row first)
        attn_kernel<<<NN / 4, 256, 0, stream>>>(q, k, v, ee, row_ptr, csr_src, csr_aid, q);
        // xr = h @ Ws + bs, into k (dead after attn)
        gemm_mfma<1><<<dim3(4, 256), 256, 0, stream>>>(
            hbf, Wlt + (size_t)(l * 4 + 3) * HID * HID, bs + l * HID, k, nullptr, NN, HID, HID);
        blend_ln_kernel<<<NN / 4, 256, 0, stream>>>(h, hbf, q, k, Wbeta + (size_t)l * 3 * HID,
                                                    bbeta + l, ln_g + l * HID, ln_b + l * HID);
    }

    // out = h @ Wout + bout  (f32)
    gemm_mfma<0><<<dim3(OUT_DIM / 128, NN / 128), 256, 0, stream>>>(
        hbf, Woutbf, bout, out, nullptr, NN, HID, OUT_DIM);
}

// Round 7
// 1172.911 us; speedup vs baseline: 3.6565x; 1.1870x over previous
//
#include <hip/hip_runtime.h>
#include <math.h>

// Problem constants (fixed by the reference)
#define NN      32768
#define EE_N    262144
#define LL      4
#define HID     512
#define IN_DIM  386
#define KP_IN   416      // IN_DIM padded to multiple of 32
#define OUT_DIM 384
#define EDIM    32
#define MAX_SP  4
#define QKV_LD  1536     // interleaved q|k|v row stride (elements)

typedef __attribute__((ext_vector_type(8))) __bf16 bf16x8;
typedef __attribute__((ext_vector_type(4))) float  f32x4;

// ---------------------------------------------------------------------------
// bf16 helpers (bit-level, RNE)
// ---------------------------------------------------------------------------
__device__ __forceinline__ unsigned short f2bf(float f) {
    unsigned int u = __float_as_uint(f);
    unsigned int r = (u + 0x7FFFu + ((u >> 16) & 1u)) >> 16;
    return (unsigned short)r;
}
__device__ __forceinline__ void unpack2(unsigned int w, float& lo, float& hi) {
    lo = __uint_as_float(w << 16);
    hi = __uint_as_float(w & 0xFFFF0000u);
}

// ---------------------------------------------------------------------------
// MFMA GEMM: C[M,N] = A[M,Kp](bf16) @ Bt[N,Kp](bf16)^T + bias[N](f32)
// 128x128 tile, BK=32, 4 waves, each wave 64x64 via 4x4 frags of 16x16x32.
// global_load_lds width=16 staging; LDS slot-swizzle on the GLOBAL source
// (dest linear, G21), matched on ds_read -> 2-way banking (free).
// Chunked-bijective XCD swizzle (nwg%8==0 for all our grids).
// OUT_MODE: 0 = f32 C0;  1 = bf16 C0;  2 = f32 C0 + bf16 C1.
// ldc = C row stride in elements (enables strided writes into qkv slots).
// ---------------------------------------------------------------------------
template <int OUT_MODE>
__global__ __launch_bounds__(256) void gemm_mfma(
    const unsigned short* __restrict__ A,   // [M][Kp] bf16 row-major
    const unsigned short* __restrict__ Bt,  // [N][Kp] bf16 (W transposed)
    const float* __restrict__ bias,
    void* __restrict__ C0, void* __restrict__ C1,
    int M, int Kp, int N, int ldc)
{
    __shared__ unsigned short As[128 * 32];  // row r at byte r*64, 4 slots of 16B
    __shared__ unsigned short Bs[128 * 32];  // col c at byte c*64

    const int t    = threadIdx.x;
    const int lane = t & 63, wid = t >> 6;
    const int wr   = wid >> 1, wc = wid & 1;        // 2x2 wave grid

    // XCD-aware chunked swizzle (bijective when nwg % 8 == 0)
    const int nwg = gridDim.x * gridDim.y;
    int bid = blockIdx.y * gridDim.x + blockIdx.x;
    if ((nwg & 7) == 0) bid = (bid & 7) * (nwg >> 3) + (bid >> 3);
    const int row0 = (bid / gridDim.x) * 128;
    const int col0 = (bid % gridDim.x) * 128;

    f32x4 acc[4][4] = {};

    const int srow  = lane >> 2;   // staging: 4 lanes per row (4x16B = 64B row)
    const int sslot = lane & 3;
    const int kq    = lane >> 4;   // ds_read k-quarter (0..3)
    const int l15   = lane & 15;

    for (int kt = 0; kt < Kp; kt += 32) {
#pragma unroll
        for (int i = 0; i < 2; ++i) {
            const int rbase = wid * 32 + i * 16;
            {   // A tile rows [rbase, rbase+16)
                const int r    = rbase + srow;
                const int koff = sslot ^ ((r >> 1) & 3);
                const unsigned short* ga = &A[(size_t)(row0 + r) * Kp + kt + koff * 8];
                __builtin_amdgcn_global_load_lds(
                    (const __attribute__((address_space(1))) unsigned int*)ga,
                    (__attribute__((address_space(3))) unsigned int*)&As[rbase * 32],
                    16, 0, 0);
            }
            {   // B tile cols [rbase, rbase+16)
                const int c    = rbase + srow;
                const int koff = sslot ^ ((c >> 1) & 3);
                const unsigned short* gb = &Bt[(size_t)(col0 + c) * Kp + kt + koff * 8];
                __builtin_amdgcn_global_load_lds(
                    (const __attribute__((address_space(1))) unsigned int*)gb,
                    (__attribute__((address_space(3))) unsigned int*)&Bs[rbase * 32],
                    16, 0, 0);
            }
        }
        __syncthreads();   // compiler drains vmcnt+lgkmcnt before s_barrier

        bf16x8 af[4], bfr[4];
#pragma unroll
        for (int mi = 0; mi < 4; ++mi) {
            const int r    = wr * 64 + mi * 16 + l15;
            const int slot = kq ^ ((r >> 1) & 3);
            af[mi] = *reinterpret_cast<const bf16x8*>(&As[r * 32 + slot * 8]);
        }
#pragma unroll
        for (int ni = 0; ni < 4; ++ni) {
            const int c    = wc * 64 + ni * 16 + l15;
            const int slot = kq ^ ((c >> 1) & 3);
            bfr[ni] = *reinterpret_cast<const bf16x8*>(&Bs[c * 32 + slot * 8]);
        }
#pragma unroll
        for (int mi = 0; mi < 4; ++mi)
#pragma unroll
            for (int ni = 0; ni < 4; ++ni)
                acc[mi][ni] = __builtin_amdgcn_mfma_f32_16x16x32_bf16(
                    af[mi], bfr[ni], acc[mi][ni], 0, 0, 0);
        __syncthreads();
    }

    // epilogue: D frag layout col=lane&15, row=(lane>>4)*4+r  [m89-verified]
    const int cb = col0 + wc * 64;
    const int rb = row0 + wr * 64;
    float bv[4];
#pragma unroll
    for (int ni = 0; ni < 4; ++ni) bv[ni] = bias[cb + ni * 16 + l15];

#pragma unroll
    for (int mi = 0; mi < 4; ++mi) {
#pragma unroll
        for (int ni = 0; ni < 4; ++ni) {
            const int col = cb + ni * 16 + l15;
#pragma unroll
            for (int r = 0; r < 4; ++r) {
                const int row = rb + mi * 16 + kq * 4 + r;
                const float oval = acc[mi][ni][r] + bv[ni];
                if (OUT_MODE == 0) {
                    ((float*)C0)[(size_t)row * ldc + col] = oval;
                } else if (OUT_MODE == 1) {
                    ((unsigned short*)C0)[(size_t)row * ldc + col] = f2bf(oval);
                } else {
                    ((float*)C0)[(size_t)row * ldc + col] = oval;
                    ((unsigned short*)C1)[(size_t)row * ldc + col] = f2bf(oval);
                }
            }
        }
    }
}

// ---------------------------------------------------------------------------
// Weight convert+transpose: Wt[n][k] = bf16(W[k][n]), zero-pad k in [K, Kp)
// ---------------------------------------------------------------------------
__global__ __launch_bounds__(256) void convert_wt(
    const float* __restrict__ W, unsigned short* __restrict__ Wt,
    int K, int N, int Kp)
{
    __shared__ float tile[32][33];
    const int tx = threadIdx.x, ty = threadIdx.y;
    const int kb = blockIdx.y * 32, nb = blockIdx.x * 32;
#pragma unroll
    for (int i = 0; i < 32; i += 8) {
        const int k = kb + ty + i, n = nb + tx;
        tile[ty + i][tx] = (k < K && n < N) ? W[(size_t)k * N + n] : 0.f;
    }
    __syncthreads();
#pragma unroll
    for (int i = 0; i < 32; i += 8) {
        const int n = nb + ty + i, k = kb + tx;
        if (n < N && k < Kp)
            Wt[(size_t)n * Kp + k] = f2bf(tile[tx][ty + i]);
    }
}

// Batched: all 16 per-layer HID x HID weights in one launch.
// blockIdx.z = l*4 + t, t in {q,k,v,s}; output at Wlt + z*HID*HID.
__global__ __launch_bounds__(256) void convert_wt_batch(
    const float* __restrict__ Wq, const float* __restrict__ Wk,
    const float* __restrict__ Wv, const float* __restrict__ Ws,
    unsigned short* __restrict__ Wlt)
{
    __shared__ float tile[32][33];
    const int m = blockIdx.z;
    const int l = m >> 2, tp = m & 3;
    const float* W = (tp == 0 ? Wq : tp == 1 ? Wk : tp == 2 ? Wv : Ws)
                     + (size_t)l * HID * HID;
    unsigned short* Wt = Wlt + (size_t)m * HID * HID;
    const int tx = threadIdx.x, ty = threadIdx.y;
    const int kb = blockIdx.y * 32, nb = blockIdx.x * 32;
#pragma unroll
    for (int i = 0; i < 32; i += 8)
        tile[ty + i][tx] = W[(size_t)(kb + ty + i) * HID + nb + tx];
    __syncthreads();
#pragma unroll
    for (int i = 0; i < 32; i += 8)
        Wt[(size_t)(nb + ty + i) * HID + kb + tx] = f2bf(tile[tx][ty + i]);
}

// emb [NN][386] f32 -> ebf [NN][416] bf16 zero-padded
__global__ __launch_bounds__(256) void convert_emb(
    const float* __restrict__ emb, unsigned short* __restrict__ ebf)
{
    const int n = blockIdx.x;
    for (int k = threadIdx.x; k < KP_IN; k += 256)
        ebf[(size_t)n * KP_IN + k] =
            (k < IN_DIM) ? f2bf(emb[(size_t)n * IN_DIM + k]) : (unsigned short)0;
}

// ---------------------------------------------------------------------------
// ee tables, all layers in one launch: ee4[l][a][j] = Etab[a]@We[l] + be[l]
// ---------------------------------------------------------------------------
__global__ void ee_all_kernel(const float* __restrict__ Etab,
                              const float* __restrict__ We,
                              const float* __restrict__ be,
                              float* __restrict__ ee4)
{
    const int l = blockIdx.x, j = threadIdx.x;
    const float* Wel = We + (size_t)l * EDIM * HID;
    const float  bel = be[(size_t)l * HID + j];
    for (int a = 0; a < MAX_SP; ++a) {
        float s = bel;
        for (int kk = 0; kk < EDIM; ++kk)
            s = fmaf(Etab[a * EDIM + kk], Wel[(size_t)kk * HID + j], s);
        ee4[((size_t)l * MAX_SP + a) * HID + j] = s;
    }
}

// fused bias for QKV GEMM: bqkv[l][0:512)=bq[l], [512:1024)=bk[l], [1024:1536)=bv[l]
__global__ void bias_fuse_kernel(const float* __restrict__ bq,
                                 const float* __restrict__ bk,
                                 const float* __restrict__ bv,
                                 float* __restrict__ bqkv)
{
    const int i = blockIdx.x * 256 + threadIdx.x;   // < LL*1536
    const int l = i / QKV_LD, r = i % QKV_LD;
    float val = (r < 512) ? bq[l * 512 + r]
              : (r < 1024) ? bk[l * 512 + r - 512]
                           : bv[l * 512 + r - 1024];
    bqkv[i] = val;
}

// ---------------------------------------------------------------------------
// CSR build: histogram -> scan -> scatter (src|aid packed into one int)
// ---------------------------------------------------------------------------
__global__ void hist_kernel(const int* __restrict__ dst, int* __restrict__ deg)
{
    int e = blockIdx.x * blockDim.x + threadIdx.x;
    if (e < EE_N) atomicAdd(&deg[dst[e]], 1);
}

__global__ __launch_bounds__(1024) void scan_kernel(
    const int* __restrict__ deg, int* __restrict__ row_ptr, int* __restrict__ cursor)
{
    __shared__ int sdata[1024];
    const int t = threadIdx.x;
    const int base = t * 32;   // 1024 * 32 == 32768
    int s = 0;
    for (int i = 0; i < 32; ++i) s += deg[base + i];
    sdata[t] = s;
    __syncthreads();
    for (int off = 1; off < 1024; off <<= 1) {
        int val = (t >= off) ? sdata[t - off] : 0;
        __syncthreads();
        sdata[t] += val;
        __syncthreads();
    }
    int run = sdata[t] - s;   // exclusive prefix
    for (int i = 0; i < 32; ++i) {
        row_ptr[base + i] = run;
        cursor[base + i]  = run;
        run += deg[base + i];
    }
    if (t == 1023) row_ptr[NN] = run;
}

__global__ void scatter_kernel(const int* __restrict__ src, const int* __restrict__ dst,
                               const int* __restrict__ aid, int* __restrict__ cursor,
                               int* __restrict__ csr_pack)
{
    int e = blockIdx.x * blockDim.x + threadIdx.x;
    if (e < EE_N) {
        int d = dst[e];
        int pos = atomicAdd(&cursor[d], 1);
        csr_pack[pos] = src[e] | (aid[e] << 16);
    }
}

// ---------------------------------------------------------------------------
// Attention over interleaved qkv [NN][1536] (q|k|v). One wave per dst node.
// No online-max (|alpha| is small; exact softmax ratio preserved).
// Writes the result over the node's q slot (own-row only).
// ---------------------------------------------------------------------------
__global__ __launch_bounds__(256) void attn_kernel(
    unsigned short* __restrict__ qkv, const float* __restrict__ ee,
    const int* __restrict__ row_ptr, const int* __restrict__ csr_pack)
{
    __shared__ float ees[MAX_SP * HID];
    const int t = threadIdx.x;
    for (int i = t; i < MAX_SP * HID; i += 256) ees[i] = ee[i];
    __syncthreads();

    const int wave = t >> 6, lane = t & 63;
    const int node = blockIdx.x * 4 + wave;
    const int off  = lane << 3;               // == h*64 + dg*8

    float qa[8];
    {
        uint4 qv = *reinterpret_cast<const uint4*>(&qkv[(size_t)node * QKV_LD + off]);
        unpack2(qv.x, qa[0], qa[1]); unpack2(qv.y, qa[2], qa[3]);
        unpack2(qv.z, qa[4], qa[5]); unpack2(qv.w, qa[6], qa[7]);
    }

    float denom = 0.f;
    float acc[8] = {0.f, 0.f, 0.f, 0.f, 0.f, 0.f, 0.f, 0.f};

    const int beg = row_ptr[node], end = row_ptr[node + 1];
    for (int i = beg; i < end; ++i) {
        const int p   = csr_pack[i];
        const int s   = p & 0xFFFF;
        const int aid = p >> 16;
        const float* ep = &ees[aid * HID + off];
        const unsigned short* kp = &qkv[(size_t)s * QKV_LD + 512 + off];

        uint4 kv = *reinterpret_cast<const uint4*>(kp);
        uint4 vv = *reinterpret_cast<const uint4*>(kp + 512);

        float kj[8];
        unpack2(kv.x, kj[0], kj[1]); unpack2(kv.y, kj[2], kj[3]);
        unpack2(kv.z, kj[4], kj[5]); unpack2(kv.w, kj[6], kj[7]);
        float partial = 0.f;
#pragma unroll
        for (int j = 0; j < 8; ++j) partial = fmaf(qa[j], kj[j] + ep[j], partial);
        partial += __shfl_xor(partial, 1);
        partial += __shfl_xor(partial, 2);
        partial += __shfl_xor(partial, 4);   // full per-head dot (8 lanes/head)
        const float w = __expf(partial * 0.125f);   // 1/sqrt(64)
        denom += w;

        float vj[8];
        unpack2(vv.x, vj[0], vj[1]); unpack2(vv.y, vj[2], vj[3]);
        unpack2(vv.z, vj[4], vj[5]); unpack2(vv.w, vj[6], vj[7]);
#pragma unroll
        for (int j = 0; j < 8; ++j) acc[j] = fmaf(w, vj[j] + ep[j], acc[j]);
    }

    const float inv = (denom > 0.f) ? (1.f / denom) : 0.f;  // deg-0 node -> 0
    union { unsigned short us[8]; uint4 v4; } pk;
#pragma unroll
    for (int j = 0; j < 8; ++j) pk.us[j] = f2bf(acc[j] * inv);
    *reinterpret_cast<uint4*>(&qkv[(size_t)node * QKV_LD + off]) = pk.v4;
}

// ---------------------------------------------------------------------------
// beta-gate + residual + LayerNorm; o = qkv q-slot, xr = qkv k-slot.
// Writes h (f32) AND hbf (bf16 shadow).
// ---------------------------------------------------------------------------
__global__ __launch_bounds__(256) void blend_ln_kernel(
    float* __restrict__ h, unsigned short* __restrict__ hbf,
    const unsigned short* __restrict__ qkv, const float* __restrict__ wbeta,
    const float* __restrict__ bbeta, const float* __restrict__ ln_g,
    const float* __restrict__ ln_b)
{
    const int t = threadIdx.x;
    const int wave = t >> 6, lane = t & 63;
    const int node = blockIdx.x * 4 + wave;
    const int off  = lane << 3;

    float o8[8], x8[8], h8[8];
    {
        uint4 a = *reinterpret_cast<const uint4*>(&qkv[(size_t)node * QKV_LD + off]);
        unpack2(a.x, o8[0], o8[1]); unpack2(a.y, o8[2], o8[3]);
        unpack2(a.z, o8[4], o8[5]); unpack2(a.w, o8[6], o8[7]);
        uint4 b = *reinterpret_cast<const uint4*>(&qkv[(size_t)node * QKV_LD + 512 + off]);
        unpack2(b.x, x8[0], x8[1]); unpack2(b.y, x8[2], x8[3]);
        unpack2(b.z, x8[4], x8[5]); unpack2(b.w, x8[6], x8[7]);
        float4 c0 = *reinterpret_cast<const float4*>(&h[(size_t)node * HID + off]);
        float4 c1 = *reinterpret_cast<const float4*>(&h[(size_t)node * HID + off + 4]);
        h8[0]=c0.x; h8[1]=c0.y; h8[2]=c0.z; h8[3]=c0.w; h8[4]=c1.x; h8[5]=c1.y; h8[6]=c1.z; h8[7]=c1.w;
    }

    float p = 0.f;
#pragma unroll
    for (int j = 0; j < 8; ++j) {
        float w1 = wbeta[off + j];
        float w2 = wbeta[HID + off + j];
        float w3 = wbeta[2 * HID + off + j];
        p = fmaf(o8[j], w1 + w3, p);
        p = fmaf(x8[j], w2 - w3, p);
    }
#pragma unroll
    for (int m = 1; m <= 32; m <<= 1) p += __shfl_xor(p, m);
    const float beta = 1.f / (1.f + __expf(-(p + bbeta[0])));

    float y[8];
    float s = 0.f;
#pragma unroll
    for (int j = 0; j < 8; ++j) {
        y[j] = h8[j] + beta * x8[j] + (1.f - beta) * o8[j];
        s += y[j];
    }
#pragma unroll
    for (int m = 1; m <= 32; m <<= 1) s += __shfl_xor(s, m);
    const float mean = s * (1.f / HID);

    float vs = 0.f;
#pragma unroll
    for (int j = 0; j < 8; ++j) {
        float d = y[j] - mean;
        vs = fmaf(d, d, vs);
    }
#pragma unroll
    for (int m = 1; m <= 32; m <<= 1) vs += __shfl_xor(vs, m);
    const float rstd = rsqrtf(vs * (1.f / HID) + 1e-5f);

    float rr[8];
    union { unsigned short us[8]; uint4 v4; } pk;
#pragma unroll
    for (int j = 0; j < 8; ++j) {
        rr[j] = (y[j] - mean) * rstd * ln_g[off + j] + ln_b[off + j];
        pk.us[j] = f2bf(rr[j]);
    }
    float4 r0 = {rr[0], rr[1], rr[2], rr[3]};
    float4 r1 = {rr[4], rr[5], rr[6], rr[7]};
    *reinterpret_cast<float4*>(&h[(size_t)node * HID + off])     = r0;
    *reinterpret_cast<float4*>(&h[(size_t)node * HID + off + 4]) = r1;
    *reinterpret_cast<uint4*>(&hbf[(size_t)node * HID + off])    = pk.v4;
}

// ---------------------------------------------------------------------------
extern "C" void kernel_launch(void* const* d_in, const int* in_sizes, int n_in,
                              void* d_out, int out_size, void* d_ws, size_t ws_size,
                              hipStream_t stream)
{
    (void)in_sizes; (void)n_in; (void)out_size; (void)ws_size;
    const float* emb   = (const float*)d_in[0];
    const int*   eidx  = (const int*)d_in[1];
    const int*   aid   = (const int*)d_in[2];
    const float* Win   = (const float*)d_in[3];
    const float* bin_  = (const float*)d_in[4];
    const float* Etab  = (const float*)d_in[5];
    const float* Wq    = (const float*)d_in[6];
    const float* bq    = (const float*)d_in[7];
    const float* Wk    = (const float*)d_in[8];
    const float* bk    = (const float*)d_in[9];
    const float* Wv    = (const float*)d_in[10];
    const float* bv    = (const float*)d_in[11];
    const float* We    = (const float*)d_in[12];
    const float* be    = (const float*)d_in[13];
    const float* Ws    = (const float*)d_in[14];
    const float* bs    = (const float*)d_in[15];
    const float* Wbeta = (const float*)d_in[16];
    const float* bbeta = (const float*)d_in[17];
    const float* ln_g  = (const float*)d_in[18];
    const float* ln_b  = (const float*)d_in[19];
    const float* Wout  = (const float*)d_in[20];
    const float* bout  = (const float*)d_in[21];
    float* out = (float*)d_out;

    // workspace layout (~202 MiB, same footprint class as the passing round-3)
    char* w = (char*)d_ws;
    float* h            = (float*)w;           w += (size_t)NN * HID * 4;     // 64 MB
    unsigned short* hbf = (unsigned short*)w;  w += (size_t)NN * HID * 2;     // 32 MB
    unsigned short* qkv = (unsigned short*)w;  w += (size_t)NN * QKV_LD * 2;  // 96 MB
    unsigned short* embbf = qkv;               // overlay: dead before layer-0 GEMM
    unsigned short* Winbf  = (unsigned short*)w; w += (size_t)HID * KP_IN * 2;
    unsigned short* Wlt    = (unsigned short*)w; w += (size_t)16 * HID * HID * 2;
    unsigned short* Woutbf = (unsigned short*)w; w += (size_t)OUT_DIM * HID * 2;
    float* ee4   = (float*)w;  w += (size_t)LL * MAX_SP * HID * 4;
    float* bqkv  = (float*)w;  w += (size_t)LL * QKV_LD * 4;
    int* row_ptr = (int*)w;    w += (NN + 4) * 4;
    int* cursor  = (int*)w;    w += NN * 4;
    int* deg     = (int*)w;    w += NN * 4;
    int* csr_pack = (int*)w;   w += EE_N * 4;

    const int* src = eidx;            // edge_index[0]
    const int* dst = eidx + EE_N;     // edge_index[1]

    // CSR build (inputs restored every call -> rebuild every launch)
    hipMemsetAsync(deg, 0, NN * sizeof(int), stream);
    hist_kernel<<<EE_N / 256, 256, 0, stream>>>(dst, deg);
    scan_kernel<<<1, 1024, 0, stream>>>(deg, row_ptr, cursor);
    scatter_kernel<<<EE_N / 256, 256, 0, stream>>>(src, dst, aid, cursor, csr_pack);

    // Weight/bias/ee prep (batched)
    dim3 tb(32, 8);
    convert_wt<<<dim3(HID / 32, KP_IN / 32), tb, 0, stream>>>(Win, Winbf, IN_DIM, HID, KP_IN);
    convert_wt_batch<<<dim3(16, 16, 16), tb, 0, stream>>>(Wq, Wk, Wv, Ws, Wlt);
    convert_wt<<<dim3(OUT_DIM / 32, HID / 32), tb, 0, stream>>>(Wout, Woutbf, HID, OUT_DIM, HID);
    convert_emb<<<NN, 256, 0, stream>>>(emb, embbf);
    ee_all_kernel<<<LL, HID, 0, stream>>>(Etab, We, be, ee4);
    bias_fuse_kernel<<<LL * QKV_LD / 256, 256, 0, stream>>>(bq, bk, bv, bqkv);

    // h = emb @ Win + bin   (f32 h + bf16 hbf)
    gemm_mfma<2><<<dim3(HID / 128, NN / 128), 256, 0, stream>>>(
        embbf, Winbf, bin_, h, hbf, NN, KP_IN, HID, HID);

    for (int l = 0; l < LL; ++l) {
        // fused q|k|v GEMM into interleaved qkv
        gemm_mfma<1><<<dim3(QKV_LD / 128, NN / 128), 256, 0, stream>>>(
            hbf, Wlt + (size_t)(l * 4) * HID * HID, bqkv + (size_t)l * QKV_LD,
            qkv, nullptr, NN, HID, QKV_LD, QKV_LD);
        // attention (writes over q slot)
        attn_kernel<<<NN / 4, 256, 0, stream>>>(
            qkv, ee4 + (size_t)l * MAX_SP * HID, row_ptr, csr_pack);
        // xr = h @ Ws + bs, into the (dead) k slot, strided
        gemm_mfma<1><<<dim3(HID / 128, NN / 128), 256, 0, stream>>>(
            hbf, Wlt + (size_t)(l * 4 + 3) * HID * HID, bs + (size_t)l * HID,
            qkv + 512, nullptr, NN, HID, HID, QKV_LD);
        blend_ln_kernel<<<NN / 4, 256, 0, stream>>>(
            h, hbf, qkv, Wbeta + (size_t)l * 3 * HID, bbeta + l,
            ln_g + (size_t)l * HID, ln_b + (size_t)l * HID);
    }

    // out = h @ Wout + bout  (f32)
    gemm_mfma<0><<<dim3(OUT_DIM / 128, NN / 128), 256, 0, stream>>>(
        hbf, Woutbf, bout, out, nullptr, NN, HID, OUT_DIM, OUT_DIM);
}